// Round 6
// baseline (185.959 us; speedup 1.0000x reference)
//
#include <hip/hip_runtime.h>
#include <hip/hip_bf16.h>

#define MSEQ 2048

typedef __attribute__((ext_vector_type(8))) short short8;
typedef __attribute__((ext_vector_type(4))) short short4v;
typedef __attribute__((ext_vector_type(4))) float f32x4;

static __device__ __forceinline__ short bf16b(float f) {
    __hip_bfloat16 h = __float2bfloat16(f);   // RNE
    return *reinterpret_cast<short*>(&h);
}

// async global->LDS, 16B per lane; LDS dest = wave-uniform base + lane*16
static __device__ __forceinline__ void gl_lds16(const void* g, void* l) {
    __builtin_amdgcn_global_load_lds(
        (const __attribute__((address_space(1))) unsigned int*)g,
        (__attribute__((address_space(3))) unsigned int*)l, 16, 0, 0);
}

// ---------------- x fp32 -> bf16 ----------------
__global__ __launch_bounds__(256) void xcvt_kernel(
    const float* __restrict__ x, unsigned short* __restrict__ xb)
{
    const size_t i = ((size_t)blockIdx.x * 256 + threadIdx.x) * 8;
    const float4 a = *(const float4*)(x + i);
    const float4 b = *(const float4*)(x + i + 4);
    short8 o;
    o[0]=bf16b(a.x); o[1]=bf16b(a.y); o[2]=bf16b(a.z); o[3]=bf16b(a.w);
    o[4]=bf16b(b.x); o[5]=bf16b(b.y); o[6]=bf16b(b.z); o[7]=bf16b(b.w);
    *(short8*)(xb + i) = o;
}

// ---------------- W -> WT[n][k] bf16 (n: 0..127 Wq | 128..255 Wk | 256..767 Wv) ----------------
__global__ __launch_bounds__(256) void wtrans_kernel(
    const float* __restrict__ Wq, const float* __restrict__ Wk,
    const float* __restrict__ Wv, unsigned short* __restrict__ WT)
{
    const int nt = blockIdx.x;   // 12 tiles of 64 n
    const int kt = blockIdx.y;   // 8 tiles of 64 k
    const int t  = threadIdx.x;
    const int k0 = kt*64;

    const float* W; int ld, n0;
    if (nt < 2)      { W = Wq; ld = 128; n0 = nt*64; }
    else if (nt < 4) { W = Wk; ld = 128; n0 = (nt-2)*64; }
    else             { W = Wv; ld = 512; n0 = (nt-4)*64; }

    __shared__ unsigned short Ts[64*72];   // [n][k]

    #pragma unroll
    for (int s = 0; s < 4; ++s) {
        const int lin = s*256 + t;
        const int krow = lin >> 4, ng = lin & 15;
        const float4 v = *(const float4*)(W + (size_t)(k0+krow)*ld + n0 + ng*4);
        Ts[(ng*4+0)*72 + krow] = (unsigned short)bf16b(v.x);
        Ts[(ng*4+1)*72 + krow] = (unsigned short)bf16b(v.y);
        Ts[(ng*4+2)*72 + krow] = (unsigned short)bf16b(v.z);
        Ts[(ng*4+3)*72 + krow] = (unsigned short)bf16b(v.w);
    }
    __syncthreads();
    #pragma unroll
    for (int s = 0; s < 2; ++s) {
        const int lin = s*256 + t;
        const int nrow = lin >> 3, kg = lin & 7;
        *(short8*)(WT + (size_t)(nt*64 + nrow)*512 + k0 + kg*8) = *(const short8*)&Ts[nrow*72 + kg*8];
    }
}

// ---------------- Fused projection GEMM, bf16 MFMA ----------------
__global__ __launch_bounds__(256, 2) void proj_mfma(
    const unsigned short* __restrict__ xb, const unsigned short* __restrict__ WT,
    const float* __restrict__ bq, const float* __restrict__ bk, const float* __restrict__ bv,
    unsigned short* __restrict__ Qb, unsigned short* __restrict__ Kb, unsigned short* __restrict__ Vt)
{
    const int nt = blockIdx.x;        // 0..5 (0=Q,1=K,2..5=V)
    const int r0 = blockIdx.y * 128;  // m
    const int n0 = nt * 128;
    const int t = threadIdx.x, w = t >> 6, lane = t & 63, l15 = lane & 15, quad = lane >> 4;
    const int qh = w >> 1, chh = w & 1;

    __shared__ short smem[128*136];
    short* As = smem;                 // [128 m][32 k]
    short* Bs = smem + 128*32;        // [128 n][32 k]

    f32x4 acc[4][4];
    #pragma unroll
    for (int i = 0; i < 4; ++i)
        #pragma unroll
        for (int j = 0; j < 4; ++j) acc[i][j] = {0.f,0.f,0.f,0.f};

    const int arow = lane >> 2, akg = lane & 3;

    for (int kk = 0; kk < 512; kk += 32) {
        #pragma unroll
        for (int s = 0; s < 2; ++s) {
            const int row = w*32 + s*16 + arow;
            gl_lds16(xb + (size_t)(r0+row)*512 + kk + akg*8, As + (w*32 + s*16)*32);
            gl_lds16(WT + (size_t)(n0+row)*512 + kk + akg*8, Bs + (w*32 + s*16)*32);
        }
        __syncthreads();
        short8 Af[4], Bf[4];
        #pragma unroll
        for (int i = 0; i < 4; ++i) Af[i] = *(const short8*)&As[(qh*64 + i*16 + l15)*32 + quad*8];
        #pragma unroll
        for (int j = 0; j < 4; ++j) Bf[j] = *(const short8*)&Bs[(chh*64 + j*16 + l15)*32 + quad*8];
        #pragma unroll
        for (int i = 0; i < 4; ++i)
            #pragma unroll
            for (int j = 0; j < 4; ++j)
                acc[i][j] = __builtin_amdgcn_mfma_f32_16x16x32_bf16(Af[i], Bf[j], acc[i][j], 0, 0, 0);
        __syncthreads();
    }

    const float* bias = (nt == 0) ? bq : (nt == 1) ? bk : (bv + (nt-2)*128);
    float bj[4];
    #pragma unroll
    for (int j = 0; j < 4; ++j) bj[j] = bias[chh*64 + j*16 + l15];

    short* Ts = smem;   // [128][136]
    if (nt < 2) {
        #pragma unroll
        for (int i = 0; i < 4; ++i)
            #pragma unroll
            for (int j = 0; j < 4; ++j)
                #pragma unroll
                for (int r = 0; r < 4; ++r)
                    Ts[(qh*64 + i*16 + quad*4 + r)*136 + chh*64 + j*16 + l15] =
                        bf16b(acc[i][j][r] + bj[j]);
    } else {
        #pragma unroll
        for (int i = 0; i < 4; ++i)
            #pragma unroll
            for (int j = 0; j < 4; ++j)
                #pragma unroll
                for (int r = 0; r < 4; ++r)
                    Ts[(chh*64 + j*16 + l15)*136 + qh*64 + i*16 + quad*4 + r] =
                        bf16b(acc[i][j][r] + bj[j]);
    }
    __syncthreads();

    if (nt < 2) {
        unsigned short* Out = (nt == 0) ? Qb : Kb;
        #pragma unroll
        for (int s = 0; s < 8; ++s) {
            const int lin = s*256 + t, row = lin >> 4, seg = lin & 15;
            *(short8*)(Out + (size_t)(r0+row)*128 + seg*8) = *(const short8*)&Ts[row*136 + seg*8];
        }
    } else {
        const int b = r0 >> 11, key0 = r0 & 2047, chBase = (nt-2)*128;
        #pragma unroll
        for (int s = 0; s < 8; ++s) {
            const int lin = s*256 + t, row = lin >> 4, seg = lin & 15;
            *(short8*)(Vt + ((size_t)(b*512 + chBase + row))*MSEQ + key0 + seg*8) =
                *(const short8*)&Ts[row*136 + seg*8];
        }
    }
}

// ---------------- Fused masked attention, bf16 MFMA, LDS-diet ----------------
// S^T = K.Q^T; K/Q/V/mask fragments load DIRECTLY from global (L1/L2-served).
// Only W round-trips LDS (double-buffered -> 1 barrier/tile). wsum shuffle
// reduction hoisted out of the key loop.
__global__ __launch_bounds__(256, 4) void attn_mfma(
    const unsigned short* __restrict__ Qb, const unsigned short* __restrict__ Kb,
    const unsigned short* __restrict__ Vt, const int* __restrict__ mask,
    const float* __restrict__ gamma, float* __restrict__ out)
{
    const int m0 = blockIdx.x * 64;   // q tile (x-fastest: co-resident blocks share bh K/V stream)
    const int bh = blockIdx.y;
    const int b  = bh >> 3, h = bh & 7;
    const int t  = threadIdx.x;
    const int wave = t >> 6, lane = t & 63, l15 = lane & 15, quad = lane >> 4;
    const int qh = wave >> 1, chh = wave & 1;

    __shared__ short Ws[2*64*68];     // [q][key] double-buffered, stride 68 shorts
    __shared__ float wsl[4*64];
    __shared__ float wsums[64];

    const short8 zz = {0,0,0,0,0,0,0,0};

    // Q B-fragments (once per block, direct global): B[k=d][n=q], d=quad*8+j (quads 2/3 = 0 pad)
    short8 qfrag[4];
    #pragma unroll
    for (int c = 0; c < 4; ++c)
        qfrag[c] = (quad < 2)
            ? *(const short8*)(Qb + (size_t)(b*MSEQ + m0 + c*16 + l15)*128 + h*16 + quad*8)
            : zz;

    f32x4 acc[2][2] = {{{0.f,0.f,0.f,0.f},{0.f,0.f,0.f,0.f}},
                       {{0.f,0.f,0.f,0.f},{0.f,0.f,0.f,0.f}}};
    float wsum_acc[4] = {0.f,0.f,0.f,0.f};

    const unsigned short* Vrow0 = Vt + ((size_t)(b*512 + h*64))*MSEQ;
    constexpr float SC = 0.25f * 1.44269504f;   // fold 1/sqrt(16) into exp2 scale

    for (int kt = 0; kt < 32; ++kt) {
        const int kn0 = kt*64;
        short* Wp = Ws + (kt & 1)*64*68;

        // ---- K A-fragment direct from global: A[m=key][k=d], key=wave*16+l15 ----
        const short8 kfrag = (quad < 2)
            ? *(const short8*)(Kb + (size_t)(b*MSEQ + kn0 + wave*16 + l15)*128 + h*16 + quad*8)
            : zz;
        // mask for this lane's 4 keys (same addr across l15 -> broadcast)
        const int4 mi = *(const int4*)(mask + b*MSEQ + kn0 + wave*16 + quad*4);
        const float mk[4] = {(float)mi.x, (float)mi.y, (float)mi.z, (float)mi.w};

        // ---- scores S^T -> weights ----
        #pragma unroll
        for (int c = 0; c < 4; ++c) {
            f32x4 s = {0.f,0.f,0.f,0.f};
            s = __builtin_amdgcn_mfma_f32_16x16x32_bf16(kfrag, qfrag[c], s, 0, 0, 0);
            float w0 = mk[0] * exp2f(fmaxf(SC*s[0], 0.f));
            float w1 = mk[1] * exp2f(fmaxf(SC*s[1], 0.f));
            float w2 = mk[2] * exp2f(fmaxf(SC*s[2], 0.f));
            float w3 = mk[3] * exp2f(fmaxf(SC*s[3], 0.f));
            short4v ws4;
            ws4[0]=bf16b(w0); ws4[1]=bf16b(w1); ws4[2]=bf16b(w2); ws4[3]=bf16b(w3);
            *(short4v*)&Wp[(c*16 + l15)*68 + wave*16 + quad*4] = ws4;
            wsum_acc[c] += (w0 + w1) + (w2 + w3);
        }
        __syncthreads();

        // ---- PV: wave quadrant rows qh*32..+31, chs chh*32..+31; V direct from global ----
        short8 Af[2][2], Bf[2][2];
        #pragma unroll
        for (int si = 0; si < 2; ++si)
            #pragma unroll
            for (int kh = 0; kh < 2; ++kh)
                Af[si][kh] = *(const short8*)&Wp[((qh*2+si)*16 + l15)*68 + kh*32 + quad*8];
        #pragma unroll
        for (int ci = 0; ci < 2; ++ci)
            #pragma unroll
            for (int kh = 0; kh < 2; ++kh)
                Bf[ci][kh] = *(const short8*)(Vrow0 + ((size_t)((chh*2+ci)*16 + l15))*MSEQ
                                              + kn0 + kh*32 + quad*8);
        #pragma unroll
        for (int si = 0; si < 2; ++si)
            #pragma unroll
            for (int ci = 0; ci < 2; ++ci)
                #pragma unroll
                for (int kh = 0; kh < 2; ++kh)
                    acc[si][ci] = __builtin_amdgcn_mfma_f32_16x16x32_bf16(
                        Af[si][kh], Bf[ci][kh], acc[si][ci], 0, 0, 0);
        // no second barrier: next tile writes the OTHER Ws buffer
    }

    // ---- wsum reduction (once) ----
    #pragma unroll
    for (int c = 0; c < 4; ++c) {
        float v = wsum_acc[c];
        v += __shfl_xor(v, 16, 64);
        v += __shfl_xor(v, 32, 64);
        if (quad == 0) wsl[wave*64 + c*16 + l15] = v;
    }
    __syncthreads();
    if (t < 64) wsums[t] = (wsl[t] + wsl[64+t]) + (wsl[128+t] + wsl[192+t]);
    __syncthreads();

    const float g = gamma[0];
    #pragma unroll
    for (int si = 0; si < 2; ++si) {
        #pragma unroll
        for (int r = 0; r < 4; ++r) {
            const int row = qh*32 + si*16 + quad*4 + r;
            const float inv = g / fmaxf(wsums[row], 1e-20f);
            #pragma unroll
            for (int ci = 0; ci < 2; ++ci) {
                const int col = chh*32 + ci*16 + l15;
                out[(size_t)(b*MSEQ + m0 + row)*512 + h*64 + col] = acc[si][ci][r] * inv;
            }
        }
    }
}

extern "C" void kernel_launch(void* const* d_in, const int* in_sizes, int n_in,
                              void* d_out, int out_size, void* d_ws, size_t ws_size,
                              hipStream_t stream) {
    const float* x     = (const float*)d_in[0];
    const int*   mask  = (const int*)  d_in[1];
    const float* Wq    = (const float*)d_in[2];
    const float* bq    = (const float*)d_in[3];
    const float* Wk    = (const float*)d_in[4];
    const float* bk    = (const float*)d_in[5];
    const float* Wv    = (const float*)d_in[6];
    const float* bv    = (const float*)d_in[7];
    const float* gamma = (const float*)d_in[8];
    float* outp = (float*)d_out;

    // ws (bf16 shorts): xb 8MB | WT 0.75MB | Qb 2MB | Kb 2MB | Vt 8MB
    unsigned short* xb = (unsigned short*)d_ws;
    unsigned short* WT = xb + (size_t)8192*512;
    unsigned short* Qb = WT + (size_t)768*512;
    unsigned short* Kb = Qb + (size_t)8192*128;
    unsigned short* Vt = Kb + (size_t)8192*128;

    xcvt_kernel<<<2048, 256, 0, stream>>>(x, xb);
    wtrans_kernel<<<dim3(12, 8), 256, 0, stream>>>(Wq, Wk, Wv, WT);
    proj_mfma<<<dim3(6, 64), 256, 0, stream>>>(xb, WT, bq, bk, bv, Qb, Kb, Vt);
    attn_mfma<<<dim3(32, 32), 256, 0, stream>>>(Qb, Kb, Vt, mask, gamma, outp);
}

// Round 7
// 179.792 us; speedup vs baseline: 1.0343x; 1.0343x over previous
//
#include <hip/hip_runtime.h>
#include <hip/hip_bf16.h>

#define MSEQ 2048

typedef __attribute__((ext_vector_type(8))) short short8;
typedef __attribute__((ext_vector_type(4))) short short4v;
typedef __attribute__((ext_vector_type(4))) float f32x4;

static __device__ __forceinline__ short bf16b(float f) {
    __hip_bfloat16 h = __float2bfloat16(f);   // RNE
    return *reinterpret_cast<short*>(&h);
}

// async global->LDS, 16B per lane; LDS dest = wave-uniform base + lane*16
static __device__ __forceinline__ void gl_lds16(const void* g, void* l) {
    __builtin_amdgcn_global_load_lds(
        (const __attribute__((address_space(1))) unsigned int*)g,
        (__attribute__((address_space(3))) unsigned int*)l, 16, 0, 0);
}

// ---------------- x fp32 -> bf16 ----------------
__global__ __launch_bounds__(256) void xcvt_kernel(
    const float* __restrict__ x, unsigned short* __restrict__ xb)
{
    const size_t i = ((size_t)blockIdx.x * 256 + threadIdx.x) * 8;
    const float4 a = *(const float4*)(x + i);
    const float4 b = *(const float4*)(x + i + 4);
    short8 o;
    o[0]=bf16b(a.x); o[1]=bf16b(a.y); o[2]=bf16b(a.z); o[3]=bf16b(a.w);
    o[4]=bf16b(b.x); o[5]=bf16b(b.y); o[6]=bf16b(b.z); o[7]=bf16b(b.w);
    *(short8*)(xb + i) = o;
}

// ---------------- W -> WT[n][k] bf16 (n: 0..127 Wq | 128..255 Wk | 256..767 Wv) ----------------
__global__ __launch_bounds__(256) void wtrans_kernel(
    const float* __restrict__ Wq, const float* __restrict__ Wk,
    const float* __restrict__ Wv, unsigned short* __restrict__ WT)
{
    const int nt = blockIdx.x;   // 12 tiles of 64 n
    const int kt = blockIdx.y;   // 8 tiles of 64 k
    const int t  = threadIdx.x;
    const int k0 = kt*64;

    const float* W; int ld, n0;
    if (nt < 2)      { W = Wq; ld = 128; n0 = nt*64; }
    else if (nt < 4) { W = Wk; ld = 128; n0 = (nt-2)*64; }
    else             { W = Wv; ld = 512; n0 = (nt-4)*64; }

    __shared__ unsigned short Ts[64*72];   // [n][k]

    #pragma unroll
    for (int s = 0; s < 4; ++s) {
        const int lin = s*256 + t;
        const int krow = lin >> 4, ng = lin & 15;
        const float4 v = *(const float4*)(W + (size_t)(k0+krow)*ld + n0 + ng*4);
        Ts[(ng*4+0)*72 + krow] = (unsigned short)bf16b(v.x);
        Ts[(ng*4+1)*72 + krow] = (unsigned short)bf16b(v.y);
        Ts[(ng*4+2)*72 + krow] = (unsigned short)bf16b(v.z);
        Ts[(ng*4+3)*72 + krow] = (unsigned short)bf16b(v.w);
    }
    __syncthreads();
    #pragma unroll
    for (int s = 0; s < 2; ++s) {
        const int lin = s*256 + t;
        const int nrow = lin >> 3, kg = lin & 7;
        *(short8*)(WT + (size_t)(nt*64 + nrow)*512 + k0 + kg*8) = *(const short8*)&Ts[nrow*72 + kg*8];
    }
}

// ---------------- Fused projection GEMM, bf16 MFMA ----------------
// [Qh|Kh|Vf] = xb @ WT^T + bias.
// Qh,Kh: head-interleaved [b][h][key][16] so attn fragment reads are coalesced.
// Vf: MFMA-fragment order [b][h][kt][chh][ci][kh][lane]x8 so attn PV B-frags
// are lane-contiguous 1KB loads (fixes round-6's 16-line gathers).
__global__ __launch_bounds__(256, 2) void proj_mfma(
    const unsigned short* __restrict__ xb, const unsigned short* __restrict__ WT,
    const float* __restrict__ bq, const float* __restrict__ bk, const float* __restrict__ bv,
    unsigned short* __restrict__ Qh, unsigned short* __restrict__ Kh, unsigned short* __restrict__ Vf)
{
    const int nt = blockIdx.x;        // 0..5 (0=Q,1=K,2..5=V)
    const int r0 = blockIdx.y * 128;  // m (keys)
    const int n0 = nt * 128;
    const int t = threadIdx.x, w = t >> 6, lane = t & 63, l15 = lane & 15, quad = lane >> 4;
    const int wqh = w >> 1, wch = w & 1;

    __shared__ short smem[128*136];
    short* As = smem;                 // [128 m][32 k]
    short* Bs = smem + 128*32;        // [128 n][32 k]

    f32x4 acc[4][4];
    #pragma unroll
    for (int i = 0; i < 4; ++i)
        #pragma unroll
        for (int j = 0; j < 4; ++j) acc[i][j] = {0.f,0.f,0.f,0.f};

    const int arow = lane >> 2, akg = lane & 3;

    for (int kk = 0; kk < 512; kk += 32) {
        #pragma unroll
        for (int s = 0; s < 2; ++s) {
            const int row = w*32 + s*16 + arow;
            gl_lds16(xb + (size_t)(r0+row)*512 + kk + akg*8, As + (w*32 + s*16)*32);
            gl_lds16(WT + (size_t)(n0+row)*512 + kk + akg*8, Bs + (w*32 + s*16)*32);
        }
        __syncthreads();
        short8 Af[4], Bf[4];
        #pragma unroll
        for (int i = 0; i < 4; ++i) Af[i] = *(const short8*)&As[(wqh*64 + i*16 + l15)*32 + quad*8];
        #pragma unroll
        for (int j = 0; j < 4; ++j) Bf[j] = *(const short8*)&Bs[(wch*64 + j*16 + l15)*32 + quad*8];
        #pragma unroll
        for (int i = 0; i < 4; ++i)
            #pragma unroll
            for (int j = 0; j < 4; ++j)
                acc[i][j] = __builtin_amdgcn_mfma_f32_16x16x32_bf16(Af[i], Bf[j], acc[i][j], 0, 0, 0);
        __syncthreads();
    }

    const float* bias = (nt == 0) ? bq : (nt == 1) ? bk : (bv + (nt-2)*128);
    float bj[4];
    #pragma unroll
    for (int j = 0; j < 4; ++j) bj[j] = bias[wch*64 + j*16 + l15];

    short* Ts = smem;   // [128][136]
    if (nt < 2) {       // row-major [m=key][n = h*16+d]
        #pragma unroll
        for (int i = 0; i < 4; ++i)
            #pragma unroll
            for (int j = 0; j < 4; ++j)
                #pragma unroll
                for (int r = 0; r < 4; ++r)
                    Ts[(wqh*64 + i*16 + quad*4 + r)*136 + wch*64 + j*16 + l15] =
                        bf16b(acc[i][j][r] + bj[j]);
    } else {            // transposed [n=ch_local][m=key_local]
        #pragma unroll
        for (int i = 0; i < 4; ++i)
            #pragma unroll
            for (int j = 0; j < 4; ++j)
                #pragma unroll
                for (int r = 0; r < 4; ++r)
                    Ts[(wch*64 + j*16 + l15)*136 + wqh*64 + i*16 + quad*4 + r] =
                        bf16b(acc[i][j][r] + bj[j]);
    }
    __syncthreads();

    const int b = r0 >> 11, key0 = r0 & 2047;
    if (nt < 2) {
        unsigned short* Out = (nt == 0) ? Qh : Kh;
        #pragma unroll
        for (int s = 0; s < 8; ++s) {
            const int lin = s*256 + t, row = lin >> 4, seg = lin & 15;
            const int h = seg >> 1, dh = seg & 1;
            *(short8*)(Out + ((size_t)(b*8 + h)*MSEQ + key0 + row)*16 + dh*8) =
                *(const short8*)&Ts[row*136 + seg*8];
        }
    } else {
        const int kt0 = key0 >> 6, h0 = (nt-2)*2;
        #pragma unroll
        for (int s = 0; s < 8; ++s) {
            const int lin = s*256 + t;
            const int lane_ = lin & 63, kh = (lin>>6)&1, ci = (lin>>7)&1;
            const int chh = (lin>>8)&1, kt_l = (lin>>9)&1, h_l = (lin>>10)&1;
            const int l15_ = lane_ & 15, quad_ = lane_ >> 4;
            const int ch_local  = h_l*64 + (chh*2+ci)*16 + l15_;
            const int key_local = kt_l*64 + kh*32 + quad_*8;
            const size_t addr = ((((((size_t)(b*8 + h0 + h_l)*32 + kt0 + kt_l)*2 + chh)*2 + ci)*2 + kh)*512)
                                + lane_*8;
            *(short8*)(Vf + addr) = *(const short8*)&Ts[ch_local*136 + key_local];
        }
    }
}

// ---------------- Fused masked attention, bf16 MFMA ----------------
// S^T = K.Q^T; Q/K from head-interleaved layout, V from fragment-order layout
// (all coalesced global, L2/L3-served). Only W round-trips LDS (double-buffered,
// stride 68 = 0 conflicts, 1 barrier/tile). wsum reduction hoisted out of loop.
__global__ __launch_bounds__(256, 4) void attn_mfma(
    const unsigned short* __restrict__ Qh, const unsigned short* __restrict__ Kh,
    const unsigned short* __restrict__ Vf, const int* __restrict__ mask,
    const float* __restrict__ gamma, float* __restrict__ out)
{
    const int m0 = blockIdx.x * 64;   // q tile
    const int bh = blockIdx.y;
    const int b  = bh >> 3, h = bh & 7;
    const int t  = threadIdx.x;
    const int wave = t >> 6, lane = t & 63, l15 = lane & 15, quad = lane >> 4;
    const int qh = wave >> 1, chh = wave & 1;

    __shared__ short Ws[2*64*68];     // [q][key] double-buffered, stride 68
    __shared__ float wsl[4*64];
    __shared__ float wsums[64];

    const short8 zz = {0,0,0,0,0,0,0,0};

    const unsigned short* Qrow = Qh + (size_t)(b*8 + h)*MSEQ*16;
    const unsigned short* Krow = Kh + (size_t)(b*8 + h)*MSEQ*16;
    const unsigned short* Vbh  = Vf + (size_t)(b*8 + h)*32*4096;

    // Q B-fragments (once per block): B[k=d][n=q], quads 2/3 = zero pad (K=16->32)
    short8 qfrag[4];
    #pragma unroll
    for (int c = 0; c < 4; ++c)
        qfrag[c] = (quad < 2)
            ? *(const short8*)(Qrow + (size_t)(m0 + c*16 + l15)*16 + quad*8)
            : zz;

    f32x4 acc[2][2] = {{{0.f,0.f,0.f,0.f},{0.f,0.f,0.f,0.f}},
                       {{0.f,0.f,0.f,0.f},{0.f,0.f,0.f,0.f}}};
    float wsum_acc[4] = {0.f,0.f,0.f,0.f};
    constexpr float SC = 0.25f * 1.44269504f;   // 1/sqrt(16) folded into exp2 scale

    for (int kt = 0; kt < 32; ++kt) {
        const int kn0 = kt*64;
        short* Wp = Ws + (kt & 1)*64*68;

        // K A-fragment: A[m=key=wave*16+l15][k=d]
        const short8 kfrag = (quad < 2)
            ? *(const short8*)(Krow + (size_t)(kn0 + wave*16 + l15)*16 + quad*8)
            : zz;
        const int4 mi = *(const int4*)(mask + b*MSEQ + kn0 + wave*16 + quad*4);
        const float mk[4] = {(float)mi.x, (float)mi.y, (float)mi.z, (float)mi.w};

        // ---- scores S^T -> weights ----
        #pragma unroll
        for (int c = 0; c < 4; ++c) {
            f32x4 s = {0.f,0.f,0.f,0.f};
            s = __builtin_amdgcn_mfma_f32_16x16x32_bf16(kfrag, qfrag[c], s, 0, 0, 0);
            float w0 = mk[0] * exp2f(fmaxf(SC*s[0], 0.f));
            float w1 = mk[1] * exp2f(fmaxf(SC*s[1], 0.f));
            float w2 = mk[2] * exp2f(fmaxf(SC*s[2], 0.f));
            float w3 = mk[3] * exp2f(fmaxf(SC*s[3], 0.f));
            short4v ws4;
            ws4[0]=bf16b(w0); ws4[1]=bf16b(w1); ws4[2]=bf16b(w2); ws4[3]=bf16b(w3);
            *(short4v*)&Wp[(c*16 + l15)*68 + wave*16 + quad*4] = ws4;
            wsum_acc[c] += (w0 + w1) + (w2 + w3);
        }

        // ---- V B-fragments (coalesced, issued pre-barrier to hide latency) ----
        short8 Bf[2][2];
        #pragma unroll
        for (int ci = 0; ci < 2; ++ci)
            #pragma unroll
            for (int kh = 0; kh < 2; ++kh)
                Bf[ci][kh] = *(const short8*)(Vbh
                    + (size_t)((((kt*2 + chh)*2 + ci)*2 + kh))*512 + lane*8);

        __syncthreads();

        // ---- PV: wave quadrant rows qh*32..+31, chs chh*32..+31 ----
        short8 Af[2][2];
        #pragma unroll
        for (int si = 0; si < 2; ++si)
            #pragma unroll
            for (int kh = 0; kh < 2; ++kh)
                Af[si][kh] = *(const short8*)&Wp[((qh*2+si)*16 + l15)*68 + kh*32 + quad*8];
        #pragma unroll
        for (int si = 0; si < 2; ++si)
            #pragma unroll
            for (int ci = 0; ci < 2; ++ci)
                #pragma unroll
                for (int kh = 0; kh < 2; ++kh)
                    acc[si][ci] = __builtin_amdgcn_mfma_f32_16x16x32_bf16(
                        Af[si][kh], Bf[ci][kh], acc[si][ci], 0, 0, 0);
        // no second barrier: next tile writes the OTHER Ws buffer
    }

    // ---- wsum reduction (once) ----
    #pragma unroll
    for (int c = 0; c < 4; ++c) {
        float v = wsum_acc[c];
        v += __shfl_xor(v, 16, 64);
        v += __shfl_xor(v, 32, 64);
        if (quad == 0) wsl[wave*64 + c*16 + l15] = v;
    }
    __syncthreads();
    if (t < 64) wsums[t] = (wsl[t] + wsl[64+t]) + (wsl[128+t] + wsl[192+t]);
    __syncthreads();

    const float g = gamma[0];
    #pragma unroll
    for (int si = 0; si < 2; ++si) {
        #pragma unroll
        for (int r = 0; r < 4; ++r) {
            const int row = qh*32 + si*16 + quad*4 + r;
            const float inv = g / fmaxf(wsums[row], 1e-20f);
            #pragma unroll
            for (int ci = 0; ci < 2; ++ci) {
                const int col = chh*32 + ci*16 + l15;
                out[(size_t)(b*MSEQ + m0 + row)*512 + h*64 + col] = acc[si][ci][r] * inv;
            }
        }
    }
}

extern "C" void kernel_launch(void* const* d_in, const int* in_sizes, int n_in,
                              void* d_out, int out_size, void* d_ws, size_t ws_size,
                              hipStream_t stream) {
    const float* x     = (const float*)d_in[0];
    const int*   mask  = (const int*)  d_in[1];
    const float* Wq    = (const float*)d_in[2];
    const float* bq    = (const float*)d_in[3];
    const float* Wk    = (const float*)d_in[4];
    const float* bk    = (const float*)d_in[5];
    const float* Wv    = (const float*)d_in[6];
    const float* bv    = (const float*)d_in[7];
    const float* gamma = (const float*)d_in[8];
    float* outp = (float*)d_out;

    // ws (bf16 shorts): xb 8MB | WT 0.75MB | Qh 2MB | Kh 2MB | Vf 8MB
    unsigned short* xb = (unsigned short*)d_ws;
    unsigned short* WT = xb + (size_t)8192*512;
    unsigned short* Qh = WT + (size_t)768*512;
    unsigned short* Kh = Qh + (size_t)8192*128;
    unsigned short* Vf = Kh + (size_t)8192*128;

    xcvt_kernel<<<2048, 256, 0, stream>>>(x, xb);
    wtrans_kernel<<<dim3(12, 8), 256, 0, stream>>>(Wq, Wk, Wv, WT);
    proj_mfma<<<dim3(6, 64), 256, 0, stream>>>(xb, WT, bq, bk, bv, Qh, Kh, Vf);
    attn_mfma<<<dim3(32, 32), 256, 0, stream>>>(Qh, Kh, Vf, mask, gamma, outp);
}

// Round 8
// 174.139 us; speedup vs baseline: 1.0679x; 1.0325x over previous
//
#include <hip/hip_runtime.h>
#include <hip/hip_bf16.h>

#define MSEQ 2048

typedef __attribute__((ext_vector_type(8))) short short8;
typedef __attribute__((ext_vector_type(4))) float f32x4;

static __device__ __forceinline__ short bf16b(float f) {
    __hip_bfloat16 h = __float2bfloat16(f);   // RNE
    return *reinterpret_cast<short*>(&h);
}

// pack 2 fp32 -> 2 bf16 (RNE, single v_cvt_pk_bf16_f32 on gfx950)
static __device__ __forceinline__ unsigned int pk2(float a, float b) {
    float2 f2; f2.x = a; f2.y = b;
    __hip_bfloat162 p = __float22bfloat162_rn(f2);
    return *reinterpret_cast<unsigned int*>(&p);
}

// async global->LDS, 16B per lane; LDS dest = wave-uniform base + lane*16
static __device__ __forceinline__ void gl_lds16(const void* g, void* l) {
    __builtin_amdgcn_global_load_lds(
        (const __attribute__((address_space(1))) unsigned int*)g,
        (__attribute__((address_space(3))) unsigned int*)l, 16, 0, 0);
}

// ---------------- W -> WT[n][k] bf16 (n: 0..127 Wq | 128..255 Wk | 256..767 Wv) ----------------
__global__ __launch_bounds__(256) void wtrans_kernel(
    const float* __restrict__ Wq, const float* __restrict__ Wk,
    const float* __restrict__ Wv, unsigned short* __restrict__ WT)
{
    const int nt = blockIdx.x;   // 12 tiles of 64 n
    const int kt = blockIdx.y;   // 8 tiles of 64 k
    const int t  = threadIdx.x;
    const int k0 = kt*64;

    const float* W; int ld, n0;
    if (nt < 2)      { W = Wq; ld = 128; n0 = nt*64; }
    else if (nt < 4) { W = Wk; ld = 128; n0 = (nt-2)*64; }
    else             { W = Wv; ld = 512; n0 = (nt-4)*64; }

    __shared__ unsigned short Ts[64*72];   // [n][k]

    #pragma unroll
    for (int s = 0; s < 4; ++s) {
        const int lin = s*256 + t;
        const int krow = lin >> 4, ng = lin & 15;
        const float4 v = *(const float4*)(W + (size_t)(k0+krow)*ld + n0 + ng*4);
        Ts[(ng*4+0)*72 + krow] = (unsigned short)bf16b(v.x);
        Ts[(ng*4+1)*72 + krow] = (unsigned short)bf16b(v.y);
        Ts[(ng*4+2)*72 + krow] = (unsigned short)bf16b(v.z);
        Ts[(ng*4+3)*72 + krow] = (unsigned short)bf16b(v.w);
    }
    __syncthreads();
    #pragma unroll
    for (int s = 0; s < 2; ++s) {
        const int lin = s*256 + t;
        const int nrow = lin >> 3, kg = lin & 7;
        *(short8*)(WT + (size_t)(nt*64 + nrow)*512 + k0 + kg*8) = *(const short8*)&Ts[nrow*72 + kg*8];
    }
}

// ---------------- Fused projection GEMM, bf16 MFMA ----------------
// [Qh|Kh|Vf] = x @ WT^T + bias.  x read DIRECTLY as fp32; A-tile converted
// in-register (cvt_pk) + ds_write_b64 (no transpose needed, conflict-free)
// -> the xcvt kernel and its 24MB pass are gone.  B staged via gl_lds16.
// Outputs: Qh,Kh head-interleaved [b][h][key][16]; Vf MFMA-fragment order.
__global__ __launch_bounds__(256, 2) void proj_mfma(
    const float* __restrict__ x, const unsigned short* __restrict__ WT,
    const float* __restrict__ bq, const float* __restrict__ bk, const float* __restrict__ bv,
    unsigned short* __restrict__ Qh, unsigned short* __restrict__ Kh, unsigned short* __restrict__ Vf)
{
    const int nt = blockIdx.x;        // 0..5 (0=Q,1=K,2..5=V)
    const int r0 = blockIdx.y * 128;  // m (keys)
    const int n0 = nt * 128;
    const int t = threadIdx.x, w = t >> 6, lane = t & 63, l15 = lane & 15, quad = lane >> 4;
    const int wqh = w >> 1, wch = w & 1;

    __shared__ short smem[128*136];
    short* As = smem;                 // [128 m][32 k]
    short* Bs = smem + 128*32;        // [128 n][32 k]

    f32x4 acc[4][4];
    #pragma unroll
    for (int i = 0; i < 4; ++i)
        #pragma unroll
        for (int j = 0; j < 4; ++j) acc[i][j] = {0.f,0.f,0.f,0.f};

    const int brow = lane >> 2, bkg = lane & 3;

    for (int kk = 0; kk < 512; kk += 32) {
        // B staging (bf16, async direct-to-LDS)
        #pragma unroll
        for (int s = 0; s < 2; ++s)
            gl_lds16(WT + (size_t)(n0 + w*32 + s*16 + brow)*512 + kk + bkg*8,
                     Bs + (w*32 + s*16)*32);
        // A staging: fp32 -> bf16 in-register, coalesced b64 LDS writes
        #pragma unroll
        for (int s = 0; s < 4; ++s) {
            const int idx = s*256 + t;
            const int row = idx >> 3, cg = idx & 7;
            const float4 v = *(const float4*)(x + (size_t)(r0+row)*512 + kk + cg*4);
            uint2 uu; uu.x = pk2(v.x, v.y); uu.y = pk2(v.z, v.w);
            *(uint2*)&As[row*32 + cg*4] = uu;
        }
        __syncthreads();
        short8 Af[4], Bf[4];
        #pragma unroll
        for (int i = 0; i < 4; ++i) Af[i] = *(const short8*)&As[(wqh*64 + i*16 + l15)*32 + quad*8];
        #pragma unroll
        for (int j = 0; j < 4; ++j) Bf[j] = *(const short8*)&Bs[(wch*64 + j*16 + l15)*32 + quad*8];
        #pragma unroll
        for (int i = 0; i < 4; ++i)
            #pragma unroll
            for (int j = 0; j < 4; ++j)
                acc[i][j] = __builtin_amdgcn_mfma_f32_16x16x32_bf16(Af[i], Bf[j], acc[i][j], 0, 0, 0);
        __syncthreads();
    }

    const float* bias = (nt == 0) ? bq : (nt == 1) ? bk : (bv + (nt-2)*128);
    float bj[4];
    #pragma unroll
    for (int j = 0; j < 4; ++j) bj[j] = bias[wch*64 + j*16 + l15];

    short* Ts = smem;   // [128][136]
    if (nt < 2) {       // row-major [m=key][n = h*16+d]
        #pragma unroll
        for (int i = 0; i < 4; ++i)
            #pragma unroll
            for (int j = 0; j < 4; ++j)
                #pragma unroll
                for (int r = 0; r < 4; ++r)
                    Ts[(wqh*64 + i*16 + quad*4 + r)*136 + wch*64 + j*16 + l15] =
                        bf16b(acc[i][j][r] + bj[j]);
    } else {            // transposed [n=ch_local][m=key_local]
        #pragma unroll
        for (int i = 0; i < 4; ++i)
            #pragma unroll
            for (int j = 0; j < 4; ++j)
                #pragma unroll
                for (int r = 0; r < 4; ++r)
                    Ts[(wch*64 + j*16 + l15)*136 + wqh*64 + i*16 + quad*4 + r] =
                        bf16b(acc[i][j][r] + bj[j]);
    }
    __syncthreads();

    const int b = r0 >> 11, key0 = r0 & 2047;
    if (nt < 2) {
        unsigned short* Out = (nt == 0) ? Qh : Kh;
        #pragma unroll
        for (int s = 0; s < 8; ++s) {
            const int lin = s*256 + t, row = lin >> 4, seg = lin & 15;
            const int h = seg >> 1, dh = seg & 1;
            *(short8*)(Out + ((size_t)(b*8 + h)*MSEQ + key0 + row)*16 + dh*8) =
                *(const short8*)&Ts[row*136 + seg*8];
        }
    } else {
        const int kt0 = key0 >> 6, h0 = (nt-2)*2;
        #pragma unroll
        for (int s = 0; s < 8; ++s) {
            const int lin = s*256 + t;
            const int lane_ = lin & 63, kh = (lin>>6)&1, ci = (lin>>7)&1;
            const int chh = (lin>>8)&1, kt_l = (lin>>9)&1, h_l = (lin>>10)&1;
            const int l15_ = lane_ & 15, quad_ = lane_ >> 4;
            const int ch_local  = h_l*64 + (chh*2+ci)*16 + l15_;
            const int key_local = kt_l*64 + kh*32 + quad_*8;
            const size_t addr = ((((((size_t)(b*8 + h0 + h_l)*32 + kt0 + kt_l)*2 + chh)*2 + ci)*2 + kh)*512)
                                + lane_*8;
            *(short8*)(Vf + addr) = *(const short8*)&Ts[ch_local*136 + key_local];
        }
    }
}

// ---------------- Fused masked attention, bf16 MFMA ----------------
// S^T = K.Q^T; Q/K head-interleaved, V fragment-order (coalesced global).
// W via LDS double-buffer (1 barrier/tile, 0 conflicts). VALU diet:
// __expf (v_exp) + v_cvt_pk_bf16_f32 packing; wsum reduction hoisted.
__global__ __launch_bounds__(256, 4) void attn_mfma(
    const unsigned short* __restrict__ Qh, const unsigned short* __restrict__ Kh,
    const unsigned short* __restrict__ Vf, const int* __restrict__ mask,
    const float* __restrict__ gamma, float* __restrict__ out)
{
    const int m0 = blockIdx.x * 64;   // q tile
    const int bh = blockIdx.y;
    const int b  = bh >> 3, h = bh & 7;
    const int t  = threadIdx.x;
    const int wave = t >> 6, lane = t & 63, l15 = lane & 15, quad = lane >> 4;
    const int qh = wave >> 1, chh = wave & 1;

    __shared__ short Ws[2*64*68];     // [q][key] double-buffered, stride 68
    __shared__ float wsl[4*64];
    __shared__ float wsums[64];

    const short8 zz = {0,0,0,0,0,0,0,0};

    const unsigned short* Qrow = Qh + (size_t)(b*8 + h)*MSEQ*16;
    const unsigned short* Krow = Kh + (size_t)(b*8 + h)*MSEQ*16;
    const unsigned short* Vbh  = Vf + (size_t)(b*8 + h)*32*4096;

    // Q B-fragments (once per block): B[k=d][n=q], quads 2/3 = zero pad (K=16->32)
    short8 qfrag[4];
    #pragma unroll
    for (int c = 0; c < 4; ++c)
        qfrag[c] = (quad < 2)
            ? *(const short8*)(Qrow + (size_t)(m0 + c*16 + l15)*16 + quad*8)
            : zz;

    f32x4 acc[2][2] = {{{0.f,0.f,0.f,0.f},{0.f,0.f,0.f,0.f}},
                       {{0.f,0.f,0.f,0.f},{0.f,0.f,0.f,0.f}}};
    float wsum_acc[4] = {0.f,0.f,0.f,0.f};

    for (int kt = 0; kt < 32; ++kt) {
        const int kn0 = kt*64;
        short* Wp = Ws + (kt & 1)*64*68;

        // K A-fragment: A[m=key=wave*16+l15][k=d]
        const short8 kfrag = (quad < 2)
            ? *(const short8*)(Krow + (size_t)(kn0 + wave*16 + l15)*16 + quad*8)
            : zz;
        const int4 mi = *(const int4*)(mask + b*MSEQ + kn0 + wave*16 + quad*4);
        const float mk[4] = {(float)mi.x, (float)mi.y, (float)mi.z, (float)mi.w};

        // ---- scores S^T -> weights ----
        #pragma unroll
        for (int c = 0; c < 4; ++c) {
            f32x4 s = {0.f,0.f,0.f,0.f};
            s = __builtin_amdgcn_mfma_f32_16x16x32_bf16(kfrag, qfrag[c], s, 0, 0, 0);
            float w0 = mk[0] * __expf(fmaxf(0.25f*s[0], 0.f));
            float w1 = mk[1] * __expf(fmaxf(0.25f*s[1], 0.f));
            float w2 = mk[2] * __expf(fmaxf(0.25f*s[2], 0.f));
            float w3 = mk[3] * __expf(fmaxf(0.25f*s[3], 0.f));
            uint2 uu; uu.x = pk2(w0, w1); uu.y = pk2(w2, w3);
            *(uint2*)&Wp[(c*16 + l15)*68 + wave*16 + quad*4] = uu;
            wsum_acc[c] += (w0 + w1) + (w2 + w3);
        }

        // ---- V B-fragments (coalesced, issued pre-barrier to hide latency) ----
        short8 Bf[2][2];
        #pragma unroll
        for (int ci = 0; ci < 2; ++ci)
            #pragma unroll
            for (int kh = 0; kh < 2; ++kh)
                Bf[ci][kh] = *(const short8*)(Vbh
                    + (size_t)((((kt*2 + chh)*2 + ci)*2 + kh))*512 + lane*8);

        __syncthreads();

        // ---- PV: wave quadrant rows qh*32..+31, chs chh*32..+31 ----
        short8 Af[2][2];
        #pragma unroll
        for (int si = 0; si < 2; ++si)
            #pragma unroll
            for (int kh = 0; kh < 2; ++kh)
                Af[si][kh] = *(const short8*)&Wp[((qh*2+si)*16 + l15)*68 + kh*32 + quad*8];
        #pragma unroll
        for (int si = 0; si < 2; ++si)
            #pragma unroll
            for (int ci = 0; ci < 2; ++ci)
                #pragma unroll
                for (int kh = 0; kh < 2; ++kh)
                    acc[si][ci] = __builtin_amdgcn_mfma_f32_16x16x32_bf16(
                        Af[si][kh], Bf[ci][kh], acc[si][ci], 0, 0, 0);
        // no second barrier: next tile writes the OTHER Ws buffer
    }

    // ---- wsum reduction (once) ----
    #pragma unroll
    for (int c = 0; c < 4; ++c) {
        float v = wsum_acc[c];
        v += __shfl_xor(v, 16, 64);
        v += __shfl_xor(v, 32, 64);
        if (quad == 0) wsl[wave*64 + c*16 + l15] = v;
    }
    __syncthreads();
    if (t < 64) wsums[t] = (wsl[t] + wsl[64+t]) + (wsl[128+t] + wsl[192+t]);
    __syncthreads();

    const float g = gamma[0];
    #pragma unroll
    for (int si = 0; si < 2; ++si) {
        #pragma unroll
        for (int r = 0; r < 4; ++r) {
            const int row = qh*32 + si*16 + quad*4 + r;
            const float inv = g / fmaxf(wsums[row], 1e-20f);
            #pragma unroll
            for (int ci = 0; ci < 2; ++ci) {
                const int col = chh*32 + ci*16 + l15;
                out[(size_t)(b*MSEQ + m0 + row)*512 + h*64 + col] = acc[si][ci][r] * inv;
            }
        }
    }
}

extern "C" void kernel_launch(void* const* d_in, const int* in_sizes, int n_in,
                              void* d_out, int out_size, void* d_ws, size_t ws_size,
                              hipStream_t stream) {
    const float* x     = (const float*)d_in[0];
    const int*   mask  = (const int*)  d_in[1];
    const float* Wq    = (const float*)d_in[2];
    const float* bq    = (const float*)d_in[3];
    const float* Wk    = (const float*)d_in[4];
    const float* bk    = (const float*)d_in[5];
    const float* Wv    = (const float*)d_in[6];
    const float* bv    = (const float*)d_in[7];
    const float* gamma = (const float*)d_in[8];
    float* outp = (float*)d_out;

    // ws (bf16 shorts): WT 0.75MB | Qh 2MB | Kh 2MB | Vf 8MB
    unsigned short* WT = (unsigned short*)d_ws;
    unsigned short* Qh = WT + (size_t)768*512;
    unsigned short* Kh = Qh + (size_t)8192*128;
    unsigned short* Vf = Kh + (size_t)8192*128;

    wtrans_kernel<<<dim3(12, 8), 256, 0, stream>>>(Wq, Wk, Wv, WT);
    proj_mfma<<<dim3(6, 64), 256, 0, stream>>>(x, WT, bq, bk, bv, Qh, Kh, Vf);
    attn_mfma<<<dim3(32, 32), 256, 0, stream>>>(Qh, Kh, Vf, mask, gamma, outp);
}